// Round 2
// baseline (704.225 us; speedup 1.0000x reference)
//
#include <hip/hip_runtime.h>

// ExtractTensorPatches: x (8,32,256,256) f32, 3x3 window, stride 1, pad 1.
// Output layout (row-major reshape, NOT a transpose):
//   out[b][c][k][ho][wo] = x[b, c, ho+ki-1, wo+kj-1] (zero-padded), k = ki*3+kj
// Pure memory-bound gather: 64 MiB read + 576 MiB write => ~102 us floor @6.3TB/s.

#define BDIM 256
#define H 256
#define W 256

typedef float vfloat4 __attribute__((ext_vector_type(4)));

__global__ __launch_bounds__(BDIM) void extract_patches_kernel(
    const float* __restrict__ x, float* __restrict__ out, int n4)
{
    int idx = blockIdx.x * BDIM + threadIdx.x;
    if (idx >= n4) return;

    int e  = idx << 2;          // flat output element index (fits in int: 1.51e8)
    int wo = e & (W - 1);       // multiple of 4
    int t  = e >> 8;
    int ho = t & (H - 1);
    t >>= 8;                    // t = (b*C + c)*9 + k
    int k  = t % 9;
    int bc = t / 9;             // b*C + c
    int ki = k / 3;             // 0..2
    int kj = k - ki * 3;        // 0..2
    int hi = ho + ki - 1;

    vfloat4 v = {0.f, 0.f, 0.f, 0.f};
    if ((unsigned)hi < (unsigned)H) {
        const float* __restrict__ row = x + ((size_t)bc << 16) + (hi << 8);
        int w0 = wo + kj - 1;   // in [-1, 253]
        if (w0 >= 0 && w0 + 3 <= W - 1) {
            // interior fast path (all lanes except wave-edge boundary cases)
            v.x = row[w0];
            v.y = row[w0 + 1];
            v.z = row[w0 + 2];
            v.w = row[w0 + 3];
        } else {
            // w0 == -1 (left edge, kj=0 & wo=0) or w0 == 253 (right edge)
            if (w0 >= 0)         v.x = row[w0];
            /* w0+1 >= 0 always */ if (w0 + 1 <= W - 1) v.y = row[w0 + 1];
            if (w0 + 2 <= W - 1) v.z = row[w0 + 2];
            if (w0 + 3 <= W - 1) v.w = row[w0 + 3];
        }
    }
    // Non-temporal: 576 MiB streaming writes should not evict the reused
    // 64 MiB input from L2 (input re-read 9x across the k sweep).
    __builtin_nontemporal_store(v, reinterpret_cast<vfloat4*>(out) + idx);
}

extern "C" void kernel_launch(void* const* d_in, const int* in_sizes, int n_in,
                              void* d_out, int out_size, void* d_ws, size_t ws_size,
                              hipStream_t stream) {
    const float* x = (const float*)d_in[0];
    float* out = (float*)d_out;
    int n4 = out_size >> 2;                  // 37,748,736 float4s
    int grid = (n4 + BDIM - 1) / BDIM;       // 147,456 blocks
    extract_patches_kernel<<<grid, BDIM, 0, stream>>>(x, out, n4);
}

// Round 3
// 619.221 us; speedup vs baseline: 1.1373x; 1.1373x over previous
//
#include <hip/hip_runtime.h>

// ExtractTensorPatches: x (8,32,256,256) f32, 3x3 window, stride 1, pad 1.
// out[bc][k][ho][wo] = x[bc, ho+ki-1, wo+kj-1] (zero-padded), k = ki*3+kj.
//
// Inverted structure: one thread per INPUT float4 (bc, ho, wo4) produces all
// 9 shifted outputs. A wave (64 lanes x float4 = 256) covers exactly one row,
// so the +/-1 w-shifts come from __shfl with wave edges == padding zeros.
// Per thread: 3 aligned dwordx4 loads, 6 shuffles, 9 coalesced dwordx4 stores.
// Traffic: ~64-96 MB read + 604 MB write => ~110 us floor @ 6.3 TB/s.

#define BDIM 256

typedef float vf4 __attribute__((ext_vector_type(4)));

__global__ __launch_bounds__(BDIM) void extract_patches_kernel(
    const float* __restrict__ x, float* __restrict__ out)
{
    int idx  = blockIdx.x * BDIM + threadIdx.x;
    int lane = idx & 63;           // wo4: float4 column within the row
    int ho   = (idx >> 6) & 255;   // output row (== input center row)
    int bc   = idx >> 14;          // b*C + c, 0..255

    const float* img = x + ((size_t)bc << 16);
    float* obase = out + ((size_t)(bc * 9) << 16) + (ho << 8) + (lane << 2);

#pragma unroll
    for (int ki = 0; ki < 3; ++ki) {
        int hi = ho + ki - 1;
        vf4 r = {0.f, 0.f, 0.f, 0.f};
        if ((unsigned)hi < 256u) {   // wave-uniform branch (whole row in/out)
            r = *reinterpret_cast<const vf4*>(img + (hi << 8) + (lane << 2));
        }
        // neighbor elements across the wave; wave edge == image edge == pad 0
        float lw = __shfl_up(r.w, 1, 64);    // x[wo-1] for element 0
        float rx = __shfl_down(r.x, 1, 64);  // x[wo+4] for element 3
        if (lane == 0)  lw = 0.f;
        if (lane == 63) rx = 0.f;
        vf4 L = {lw,  r.x, r.y, r.z};        // kj = 0: x[.., wo-1 .. wo+2]
        vf4 R = {r.y, r.z, r.w, rx};         // kj = 2: x[.., wo+1 .. wo+4]

        float* o = obase + (size_t)(ki * 3) * 65536;  // k = ki*3 + kj
        *reinterpret_cast<vf4*>(o)          = L;
        *reinterpret_cast<vf4*>(o + 65536)  = r;
        *reinterpret_cast<vf4*>(o + 131072) = R;
    }
}

extern "C" void kernel_launch(void* const* d_in, const int* in_sizes, int n_in,
                              void* d_out, int out_size, void* d_ws, size_t ws_size,
                              hipStream_t stream) {
    const float* x = (const float*)d_in[0];
    float* out = (float*)d_out;
    // threads = 256 bc * 256 ho * 64 wo4 = 4,194,304 -> 16384 blocks
    int total = 256 * 256 * 64;
    int grid = total / BDIM;
    extract_patches_kernel<<<grid, BDIM, 0, stream>>>(x, out);
}